// Round 4
// baseline (22140.941 us; speedup 1.0000x reference)
//
#include <hip/hip_runtime.h>

// LSTM layer: T=512, B=64, I=1024, H=1024, fp32.
// R3 = R2 resubmitted verbatim (rounds 0/1/3 died on an unresponsive broker
// container; R2's bench showed the cooperative launch never ran -> per-step
// launches; kernel boundary IS the grid barrier).
//  1) gx_gemm: gx[t,b,r] = x[t,b,:]·W_ih[r,:] + b_ih[r] + b_hh[r], written
//     PERMUTED: gxp[trel][ublk=u/4][b][g*4 + u%4] (per-block-contiguous 4KB).
//  2) lstm_step (x512): 256 blocks x 256 threads; block cu owns hidden units
//     cu*4..cu*4+3 => 16 W_hh rows staged in XOR-swizzled LDS; h_prev read
//     from out[(t-1)*BH] (or h0), staged in 4 K-quarters into swizzled LDS
//     with register prefetch; 8x8x64 per-thread partials; shfl butterfly over
//     16 K-slices; gates; c updated in place in ws.

#define BH 65536  // B*H floats

// ----------------------------- gx GEMM --------------------------------------
#define BM 128
#define BN 128
#define BKg 16

__global__ __launch_bounds__(256, 2)
void gx_gemm(const float* __restrict__ x, const float* __restrict__ Wih,
             const float* __restrict__ bih, const float* __restrict__ bhh,
             float* __restrict__ gxp, int t0)
{
    __shared__ float As[BKg][BM + 4];
    __shared__ float Bs[BKg][BN + 4];
    const int tid  = threadIdx.x;
    const int nblk = blockIdx.x;        // 0..31
    const int mblk = blockIdx.y;        // 0..chunk/2-1
    const int lrow = tid >> 2;          // 0..63
    const int lkq  = (tid & 3) * 4;     // float4 col within k-tile
    const int ty   = tid >> 4;          // 0..15
    const int tx   = tid & 15;          // 0..15

    const float* xb = x   + ((size_t)t0 * 64 + (size_t)mblk * BM) * 1024;
    const float* wb = Wih + (size_t)nblk * BN * 1024;

    float acc[8][8] = {};
    for (int kt = 0; kt < 1024; kt += BKg) {
        const int k0 = kt + lkq;
        float4 a0 = *(const float4*)(xb + (size_t)lrow        * 1024 + k0);
        float4 a1 = *(const float4*)(xb + (size_t)(lrow + 64) * 1024 + k0);
        float4 b0 = *(const float4*)(wb + (size_t)lrow        * 1024 + k0);
        float4 b1 = *(const float4*)(wb + (size_t)(lrow + 64) * 1024 + k0);
        __syncthreads();
        As[lkq + 0][lrow] = a0.x; As[lkq + 1][lrow] = a0.y;
        As[lkq + 2][lrow] = a0.z; As[lkq + 3][lrow] = a0.w;
        As[lkq + 0][lrow + 64] = a1.x; As[lkq + 1][lrow + 64] = a1.y;
        As[lkq + 2][lrow + 64] = a1.z; As[lkq + 3][lrow + 64] = a1.w;
        Bs[lkq + 0][lrow] = b0.x; Bs[lkq + 1][lrow] = b0.y;
        Bs[lkq + 2][lrow] = b0.z; Bs[lkq + 3][lrow] = b0.w;
        Bs[lkq + 0][lrow + 64] = b1.x; Bs[lkq + 1][lrow + 64] = b1.y;
        Bs[lkq + 2][lrow + 64] = b1.z; Bs[lkq + 3][lrow + 64] = b1.w;
        __syncthreads();
        #pragma unroll
        for (int kk = 0; kk < BKg; ++kk) {
            float4 af0 = *(float4*)&As[kk][ty * 8];
            float4 af1 = *(float4*)&As[kk][ty * 8 + 4];
            float4 bf0 = *(float4*)&Bs[kk][tx * 8];
            float4 bf1 = *(float4*)&Bs[kk][tx * 8 + 4];
            float a[8] = {af0.x, af0.y, af0.z, af0.w, af1.x, af1.y, af1.z, af1.w};
            float b[8] = {bf0.x, bf0.y, bf0.z, bf0.w, bf1.x, bf1.y, bf1.z, bf1.w};
            #pragma unroll
            for (int i = 0; i < 8; ++i)
                #pragma unroll
                for (int j = 0; j < 8; ++j)
                    acc[i][j] += a[i] * b[j];
        }
    }
    float bias[8];
    #pragma unroll
    for (int j = 0; j < 8; ++j) {
        int r = nblk * BN + tx * 8 + j;
        bias[j] = bih[r] + bhh[r];
    }
    #pragma unroll
    for (int i = 0; i < 8; ++i) {
        int ml   = mblk * BM + ty * 8 + i;   // chunk-local M row
        int trel = ml >> 6, b = ml & 63;
        #pragma unroll
        for (int jj = 0; jj < 2; ++jj) {
            int r = nblk * BN + tx * 8 + jj * 4;
            int g = r >> 10, u = r & 1023;   // float4 spans ulocal 0..3, same g
            float4 v = make_float4(acc[i][jj*4+0] + bias[jj*4+0],
                                   acc[i][jj*4+1] + bias[jj*4+1],
                                   acc[i][jj*4+2] + bias[jj*4+2],
                                   acc[i][jj*4+3] + bias[jj*4+3]);
            *(float4*)(gxp + ((((size_t)trel * 256 + (u >> 2)) * 64 + b) << 4) + g * 4) = v;
        }
    }
}

// ------------------------------ one LSTM step --------------------------------
__global__ __launch_bounds__(256, 1)
void lstm_step(const float* __restrict__ Whh, const float* __restrict__ gxp,
               const float* __restrict__ hprev, const float* __restrict__ cprev,
               float* __restrict__ cbuf, float* __restrict__ out,
               int t, int trel)
{
    __shared__ float w_lds[16][1024];   // 64KB, XOR-swizzled 16B units
    __shared__ float h_lds[64][256];    // 64KB, one K-quarter, swizzled
    __shared__ float g_lds[16][66];     // gate gather

    const int tid = threadIdx.x;
    const int cu  = blockIdx.x;         // hidden units cu*4 .. cu*4+3

    // Stage W_hh slice: local row rl = g*4+ul  <->  global row g*1024 + cu*4 + ul
    #pragma unroll
    for (int rl = 0; rl < 16; ++rl) {
        int q4 = tid;                   // 16B unit 0..255
        int g = rl >> 2, ul = rl & 3;
        float4 v = *(const float4*)(Whh + ((size_t)(g * 1024 + cu * 4 + ul)) * 1024 + q4 * 4);
        int sw = q4 ^ ((q4 >> 2) & 7);
        *(float4*)&w_lds[rl][sw * 4] = v;
    }

    const int ks = tid & 15;            // K-slice 0..15
    const int bt = (tid >> 4) & 7;      // batch tile 0..7
    const int rt = tid >> 7;            // row tile 0..1
    const int eb = tid >> 2;            // elementwise batch
    const int eu = tid & 3;             // elementwise ulocal

    float4 pre[16];
    auto loadq = [&](int q) {
        #pragma unroll
        for (int i2 = 0; i2 < 16; ++i2) {
            int b = i2 * 4 + (tid >> 6);
            pre[i2] = *(const float4*)(hprev + (size_t)b * 1024 + q * 256 + (tid & 63) * 4);
        }
    };
    loadq(0);
    float acc[8][8] = {};
    for (int q = 0; q < 4; ++q) {
        __syncthreads();                // h_lds free (prev quarter consumed)
        {
            int u16 = tid & 63;
            int sw  = u16 ^ ((u16 >> 2) & 7);
            #pragma unroll
            for (int i2 = 0; i2 < 16; ++i2) {
                int b = i2 * 4 + (tid >> 6);
                *(float4*)&h_lds[b][sw * 4] = pre[i2];
            }
        }
        __syncthreads();
        if (q < 3) loadq(q + 1);        // prefetch next quarter under compute
        #pragma unroll
        for (int kk4 = 0; kk4 < 4; ++kk4) {
            int u16h = ks * 4 + kk4;
            int swh  = u16h ^ (ks & 7);
            int sww  = (q * 64 + u16h) ^ (ks & 7);
            float4 w4[8], h4[8];
            #pragma unroll
            for (int i = 0; i < 8; ++i) w4[i] = *(float4*)&w_lds[rt * 8 + i][sww * 4];
            #pragma unroll
            for (int j = 0; j < 8; ++j) h4[j] = *(float4*)&h_lds[bt * 8 + j][swh * 4];
            #pragma unroll
            for (int i = 0; i < 8; ++i)
                #pragma unroll
                for (int j = 0; j < 8; ++j)
                    acc[i][j] += w4[i].x * h4[j].x + w4[i].y * h4[j].y
                               + w4[i].z * h4[j].z + w4[i].w * h4[j].w;
        }
    }
    // butterfly-reduce the 16 K-slices (lane bits 0..3)
    #pragma unroll
    for (int d = 1; d < 16; d <<= 1)
        #pragma unroll
        for (int i = 0; i < 8; ++i)
            #pragma unroll
            for (int j = 0; j < 8; ++j)
                acc[i][j] += __shfl_xor(acc[i][j], d, 64);
    if (ks == 0) {
        #pragma unroll
        for (int i = 0; i < 8; ++i)
            #pragma unroll
            for (int j = 0; j < 8; ++j)
                g_lds[rt * 8 + i][bt * 8 + j] = acc[i][j];
    }
    __syncthreads();
    {
        float c_reg = cprev[eb * 1024 + cu * 4 + eu];
        const float* gx = gxp + (((size_t)trel * 256 + cu) * 64 + eb) * 16;
        float gi = g_lds[ 0 + eu][eb] + gx[ 0 + eu];
        float gf = g_lds[ 4 + eu][eb] + gx[ 4 + eu];
        float gg = g_lds[ 8 + eu][eb] + gx[ 8 + eu];
        float go = g_lds[12 + eu][eb] + gx[12 + eu];
        gi = 1.0f / (1.0f + __expf(-gi));
        gf = 1.0f / (1.0f + __expf(-gf));
        gg = tanhf(gg);
        go = 1.0f / (1.0f + __expf(-go));
        c_reg = gf * c_reg + gi * gg;
        float hn = go * tanhf(c_reg);
        int hcol = cu * 4 + eu;
        cbuf[eb * 1024 + hcol] = c_reg;
        out[((size_t)t * 64 + eb) * 1024 + hcol] = hn;
        if (t == 511) {
            out[(size_t)512 * BH + eb * 1024 + hcol]      = hn;     // h_fin
            out[(size_t)512 * BH + BH + eb * 1024 + hcol] = c_reg;  // c_fin
        }
    }
}

// --------------------------------- host -------------------------------------
extern "C" void kernel_launch(void* const* d_in, const int* in_sizes, int n_in,
                              void* d_out, int out_size, void* d_ws, size_t ws_size,
                              hipStream_t stream)
{
    const float* x   = (const float*)d_in[0];
    const float* h0  = (const float*)d_in[1];
    const float* c0  = (const float*)d_in[2];
    const float* Wih = (const float*)d_in[3];
    const float* Whh = (const float*)d_in[4];
    const float* bih = (const float*)d_in[5];
    const float* bhh = (const float*)d_in[6];
    float* out = (float*)d_out;

    float* cbuf = (float*)d_ws;            // BH floats (c state, in-place)
    float* gxp  = cbuf + BH;               // Tc * 64 * 4096 floats

    size_t ws_floats = ws_size / 4;
    size_t avail = (ws_floats > (size_t)BH) ? ws_floats - (size_t)BH : 0;
    long Tcl = (long)(avail / (64 * 4096));
    int Tc = (int)(Tcl > 512 ? 512 : Tcl);
    Tc &= ~1;
    if (Tc < 2) Tc = 2;   // needs ~2.4MB ws minimum

    for (int t0 = 0; t0 < 512; t0 += Tc) {
        int chunk = (512 - t0 < Tc) ? (512 - t0) : Tc;
        dim3 ggrid(32, chunk * 64 / BM);
        gx_gemm<<<ggrid, 256, 0, stream>>>(x, Wih, bih, bhh, gxp, t0);
        for (int trel = 0; trel < chunk; ++trel) {
            int t = t0 + trel;
            const float* hprev = (t == 0) ? h0 : out + (size_t)(t - 1) * BH;
            const float* cprev = (t == 0) ? c0 : cbuf;
            lstm_step<<<dim3(256), dim3(256), 0, stream>>>(
                Whh, gxp, hprev, cprev, cbuf, out, t, trel);
        }
    }
}

// Round 6
// 20890.254 us; speedup vs baseline: 1.0599x; 1.0599x over previous
//
#include <hip/hip_runtime.h>
#include <hip/hip_bf16.h>

// LSTM layer: T=512, B=64, I=1024, H=1024, fp32.
// R5 = R4 resubmit (infra ate R4) + XOR-swizzled LDS partial-reduction buffer
// (write was a 16-way bank conflict: ks-stride 4KB; swizzle -> 4-way).
//  (a) gx GEMM -> bf16x3-split MFMA (hi/lo planes, 3 products, ~fp32 acc);
//  (b) lstm_step: LDS partial reduction (no shuffle butterfly); exp-based tanh.
// Per-timestep launches (kernel boundary = grid barrier).

#define BH 65536  // B*H floats

typedef __attribute__((ext_vector_type(8))) short bf16x8;  // 8 bf16 (4 VGPRs)
typedef __attribute__((ext_vector_type(4))) float f32x4;

__device__ inline ushort f2bf(float x) {
    __hip_bfloat16 b = __float2bfloat16(x);
    return *(ushort*)&b;
}
__device__ inline float bf2f(ushort u) {
    __hip_bfloat16 b = *(__hip_bfloat16*)&u;
    return __bfloat162float(b);
}

// ---------------- fp32 -> (hi,lo) bf16 planes (grid-stride) -----------------
__global__ void split_bf16(const float* __restrict__ src,
                           ushort* __restrict__ hi, ushort* __restrict__ lo,
                           long n)
{
    long i0 = ((long)blockIdx.x * blockDim.x + threadIdx.x) * 4;
    long stride = (long)gridDim.x * blockDim.x * 4;
    for (long e = i0; e < n; e += stride) {
        float4 v = *(const float4*)(src + e);
        ushort4 hv, lv;
        hv.x = f2bf(v.x); lv.x = f2bf(v.x - bf2f(hv.x));
        hv.y = f2bf(v.y); lv.y = f2bf(v.y - bf2f(hv.y));
        hv.z = f2bf(v.z); lv.z = f2bf(v.z - bf2f(hv.z));
        hv.w = f2bf(v.w); lv.w = f2bf(v.w - bf2f(hv.w));
        *(ushort4*)(hi + e) = hv;
        *(ushort4*)(lo + e) = lv;
    }
}

// ---------------- bf16x3 MFMA gx GEMM: gx = x·Wih^T + bias, permuted --------
// A = x planes [Mchunk][1024], B = Wih planes [4096][1024]; both K-contig, so
// A and B fragments load identically (B^T GEMM). 128x128 tile, BK=32, 4 waves.
__global__ __launch_bounds__(256)
void gx_mfma(const ushort* __restrict__ xhi, const ushort* __restrict__ xlo,
             const ushort* __restrict__ whi, const ushort* __restrict__ wlo,
             const float* __restrict__ bih, const float* __restrict__ bhh,
             float* __restrict__ gxp)
{
    __shared__ short lds[4][4096];      // planes Ahi,Alo,Bhi,Blo: [128][32] bf16
    const int tid  = threadIdx.x;
    const int lane = tid & 63;
    const int w    = tid >> 6;          // wave 0..3
    const int wm   = w >> 1, wn = w & 1;
    const int mt0  = blockIdx.y * 128;  // chunk-local m = trel*64 + b
    const int nt0  = blockIdx.x * 128;  // gate row r

    // staging coords: sweep s covers rows s*64 + w*16 + lane/4, col (lane&3)*8
    const int lr_ = w * 16 + (lane >> 2);
    const int lc_ = (lane & 3) * 8;

    f32x4 acc[4][4] = {};

    for (int kt = 0; kt < 1024; kt += 32) {
        uint4 rah[2], ral[2], rbh[2], rbl[2];
        #pragma unroll
        for (int s = 0; s < 2; ++s) {
            size_t ao = (size_t)(mt0 + s * 64 + lr_) * 1024 + kt + lc_;
            size_t bo = (size_t)(nt0 + s * 64 + lr_) * 1024 + kt + lc_;
            rah[s] = *(const uint4*)(xhi + ao);
            ral[s] = *(const uint4*)(xlo + ao);
            rbh[s] = *(const uint4*)(whi + bo);
            rbl[s] = *(const uint4*)(wlo + bo);
        }
        __syncthreads();
        #pragma unroll
        for (int s = 0; s < 2; ++s) {
            int off = s * 2048 + w * 512 + lane * 8;   // shorts
            *(uint4*)&lds[0][off] = rah[s];
            *(uint4*)&lds[1][off] = ral[s];
            *(uint4*)&lds[2][off] = rbh[s];
            *(uint4*)&lds[3][off] = rbl[s];
        }
        __syncthreads();
        bf16x8 ah[4], al[4], bh[4], bl[4];
        #pragma unroll
        for (int f = 0; f < 4; ++f) {
            int ar = (wm * 64 + f * 16 + (lane & 15)) * 32 + (lane >> 4) * 8;
            int br = (wn * 64 + f * 16 + (lane & 15)) * 32 + (lane >> 4) * 8;
            ah[f] = *(bf16x8*)&lds[0][ar];
            al[f] = *(bf16x8*)&lds[1][ar];
            bh[f] = *(bf16x8*)&lds[2][br];
            bl[f] = *(bf16x8*)&lds[3][br];
        }
        #pragma unroll
        for (int i = 0; i < 4; ++i)
            #pragma unroll
            for (int j = 0; j < 4; ++j) {
                acc[i][j] = __builtin_amdgcn_mfma_f32_16x16x32_bf16(ah[i], bh[j], acc[i][j], 0, 0, 0);
                acc[i][j] = __builtin_amdgcn_mfma_f32_16x16x32_bf16(ah[i], bl[j], acc[i][j], 0, 0, 0);
                acc[i][j] = __builtin_amdgcn_mfma_f32_16x16x32_bf16(al[i], bh[j], acc[i][j], 0, 0, 0);
            }
    }
    // epilogue: D[m][r]; m=(lane>>4)*4+reg within frag (m89-verified layout)
    #pragma unroll
    for (int j = 0; j < 4; ++j) {
        int r = nt0 + wn * 64 + j * 16 + (lane & 15);
        float bias = bih[r] + bhh[r];
        int g = r >> 10, u = r & 1023;
        #pragma unroll
        for (int i = 0; i < 4; ++i) {
            #pragma unroll
            for (int e = 0; e < 4; ++e) {
                int m = mt0 + wm * 64 + i * 16 + (lane >> 4) * 4 + e;
                int trel = m >> 6, b = m & 63;
                gxp[(((size_t)trel * 256 + (u >> 2)) * 64 + b) * 16 + g * 4 + (u & 3)]
                    = acc[i][j][e] + bias;
            }
        }
    }
}

// ----------------------- fp32 gx GEMM (small-ws fallback) -------------------
#define BM 128
#define BN 128
#define BKg 16

__global__ __launch_bounds__(256, 2)
void gx_gemm(const float* __restrict__ x, const float* __restrict__ Wih,
             const float* __restrict__ bih, const float* __restrict__ bhh,
             float* __restrict__ gxp, int t0)
{
    __shared__ float As[BKg][BM + 4];
    __shared__ float Bs[BKg][BN + 4];
    const int tid  = threadIdx.x;
    const int nblk = blockIdx.x;
    const int mblk = blockIdx.y;
    const int lrow = tid >> 2;
    const int lkq  = (tid & 3) * 4;
    const int ty   = tid >> 4;
    const int tx   = tid & 15;

    const float* xb = x   + ((size_t)t0 * 64 + (size_t)mblk * BM) * 1024;
    const float* wb = Wih + (size_t)nblk * BN * 1024;

    float acc[8][8] = {};
    for (int kt = 0; kt < 1024; kt += BKg) {
        const int k0 = kt + lkq;
        float4 a0 = *(const float4*)(xb + (size_t)lrow        * 1024 + k0);
        float4 a1 = *(const float4*)(xb + (size_t)(lrow + 64) * 1024 + k0);
        float4 b0 = *(const float4*)(wb + (size_t)lrow        * 1024 + k0);
        float4 b1 = *(const float4*)(wb + (size_t)(lrow + 64) * 1024 + k0);
        __syncthreads();
        As[lkq + 0][lrow] = a0.x; As[lkq + 1][lrow] = a0.y;
        As[lkq + 2][lrow] = a0.z; As[lkq + 3][lrow] = a0.w;
        As[lkq + 0][lrow + 64] = a1.x; As[lkq + 1][lrow + 64] = a1.y;
        As[lkq + 2][lrow + 64] = a1.z; As[lkq + 3][lrow + 64] = a1.w;
        Bs[lkq + 0][lrow] = b0.x; Bs[lkq + 1][lrow] = b0.y;
        Bs[lkq + 2][lrow] = b0.z; Bs[lkq + 3][lrow] = b0.w;
        Bs[lkq + 0][lrow + 64] = b1.x; Bs[lkq + 1][lrow + 64] = b1.y;
        Bs[lkq + 2][lrow + 64] = b1.z; Bs[lkq + 3][lrow + 64] = b1.w;
        __syncthreads();
        #pragma unroll
        for (int kk = 0; kk < BKg; ++kk) {
            float4 af0 = *(float4*)&As[kk][ty * 8];
            float4 af1 = *(float4*)&As[kk][ty * 8 + 4];
            float4 bf0 = *(float4*)&Bs[kk][tx * 8];
            float4 bf1 = *(float4*)&Bs[kk][tx * 8 + 4];
            float a[8] = {af0.x, af0.y, af0.z, af0.w, af1.x, af1.y, af1.z, af1.w};
            float b[8] = {bf0.x, bf0.y, bf0.z, bf0.w, bf1.x, bf1.y, bf1.z, bf1.w};
            #pragma unroll
            for (int i = 0; i < 8; ++i)
                #pragma unroll
                for (int j = 0; j < 8; ++j)
                    acc[i][j] += a[i] * b[j];
        }
    }
    float bias[8];
    #pragma unroll
    for (int j = 0; j < 8; ++j) {
        int r = nblk * BN + tx * 8 + j;
        bias[j] = bih[r] + bhh[r];
    }
    #pragma unroll
    for (int i = 0; i < 8; ++i) {
        int ml   = mblk * BM + ty * 8 + i;
        int trel = ml >> 6, b = ml & 63;
        #pragma unroll
        for (int jj = 0; jj < 2; ++jj) {
            int r = nblk * BN + tx * 8 + jj * 4;
            int g = r >> 10, u = r & 1023;
            float4 v = make_float4(acc[i][jj*4+0] + bias[jj*4+0],
                                   acc[i][jj*4+1] + bias[jj*4+1],
                                   acc[i][jj*4+2] + bias[jj*4+2],
                                   acc[i][jj*4+3] + bias[jj*4+3]);
            *(float4*)(gxp + ((((size_t)trel * 256 + (u >> 2)) * 64 + b) << 4) + g * 4) = v;
        }
    }
}

// ------------------------------ one LSTM step --------------------------------
__global__ __launch_bounds__(256, 1)
void lstm_step(const float* __restrict__ Whh, const float* __restrict__ gxp,
               const float* __restrict__ hprev, const float* __restrict__ cprev,
               float* __restrict__ cbuf, float* __restrict__ out,
               int t, int trel)
{
    __shared__ float w_lds[16][1024];   // 64KB, XOR-swizzled 16B units
    __shared__ float h_lds[64][256];    // 64KB: h quarter; then partial scratch
    __shared__ float g_lds[16][68];     // gate gather

    const int tid = threadIdx.x;
    const int cu  = blockIdx.x;         // hidden units cu*4 .. cu*4+3

    // Stage W_hh slice: local row rl = g*4+ul <-> global row g*1024 + cu*4 + ul
    #pragma unroll
    for (int rl = 0; rl < 16; ++rl) {
        int q4 = tid;                   // 16B unit 0..255
        int g = rl >> 2, ul = rl & 3;
        float4 v = *(const float4*)(Whh + ((size_t)(g * 1024 + cu * 4 + ul)) * 1024 + q4 * 4);
        int sw = q4 ^ ((q4 >> 2) & 7);
        *(float4*)&w_lds[rl][sw * 4] = v;
    }

    const int ks = tid & 15;            // K-slice 0..15
    const int bt = (tid >> 4) & 7;      // batch tile 0..7
    const int rt = tid >> 7;            // row tile 0..1
    const int eb = tid >> 2;            // elementwise batch
    const int eu = tid & 3;             // elementwise ulocal

    float4 pre[16];
    auto loadq = [&](int q) {
        #pragma unroll
        for (int i2 = 0; i2 < 16; ++i2) {
            int b = i2 * 4 + (tid >> 6);
            pre[i2] = *(const float4*)(hprev + (size_t)b * 1024 + q * 256 + (tid & 63) * 4);
        }
    };
    loadq(0);
    float acc[8][8] = {};
    for (int q = 0; q < 4; ++q) {
        __syncthreads();                // h_lds free (prev quarter consumed)
        {
            int u16 = tid & 63;
            int sw  = u16 ^ ((u16 >> 2) & 7);
            #pragma unroll
            for (int i2 = 0; i2 < 16; ++i2) {
                int b = i2 * 4 + (tid >> 6);
                *(float4*)&h_lds[b][sw * 4] = pre[i2];
            }
        }
        __syncthreads();
        if (q < 3) loadq(q + 1);        // prefetch next quarter under compute
        #pragma unroll
        for (int kk4 = 0; kk4 < 4; ++kk4) {
            int u16h = ks * 4 + kk4;
            int swh  = u16h ^ (ks & 7);
            int sww  = (q * 64 + u16h) ^ (ks & 7);
            float4 w4[8], h4[8];
            #pragma unroll
            for (int i = 0; i < 8; ++i) w4[i] = *(float4*)&w_lds[rt * 8 + i][sww * 4];
            #pragma unroll
            for (int j = 0; j < 8; ++j) h4[j] = *(float4*)&h_lds[bt * 8 + j][swh * 4];
            #pragma unroll
            for (int i = 0; i < 8; ++i)
                #pragma unroll
                for (int j = 0; j < 8; ++j)
                    acc[i][j] += w4[i].x * h4[j].x + w4[i].y * h4[j].y
                               + w4[i].z * h4[j].z + w4[i].w * h4[j].w;
        }
    }
    // K-slice reduction via LDS partials. h_lds reused as part[ks][rb 1024],
    // rb = r*64 + b, stored at rb ^ ((ks&7)<<3) (bank swizzle: 16-way -> 4-way).
    float* ph = &h_lds[0][0];
    __syncthreads();                    // everyone done reading h_lds
    #pragma unroll
    for (int i = 0; i < 8; ++i) {
        int rb0 = ((rt * 8 + i) * 64 + bt * 8 + 0) ^ ((ks & 7) << 3);
        int rb1 = ((rt * 8 + i) * 64 + bt * 8 + 4) ^ ((ks & 7) << 3);
        *(float4*)(ph + ks * 1024 + rb0) =
            make_float4(acc[i][0], acc[i][1], acc[i][2], acc[i][3]);
        *(float4*)(ph + ks * 1024 + rb1) =
            make_float4(acc[i][4], acc[i][5], acc[i][6], acc[i][7]);
    }
    __syncthreads();
    {
        // thread tid sums outputs o = tid*4..tid*4+3 (r = tid>>4, b0 = (tid&15)*4)
        float4 s = *(float4*)(ph + (tid * 4));   // k2 = 0: swizzle is identity
        #pragma unroll
        for (int k2 = 1; k2 < 16; ++k2) {
            float4 p = *(float4*)(ph + k2 * 1024 + ((tid * 4) ^ ((k2 & 7) << 3)));
            s.x += p.x; s.y += p.y; s.z += p.z; s.w += p.w;
        }
        *(float4*)&g_lds[tid >> 4][(tid & 15) * 4] = s;
    }
    __syncthreads();
    {
        float c_reg = cprev[eb * 1024 + cu * 4 + eu];
        const float* gx = gxp + (((size_t)trel * 256 + cu) * 64 + eb) * 16;
        float gi = g_lds[ 0 + eu][eb] + gx[ 0 + eu];
        float gf = g_lds[ 4 + eu][eb] + gx[ 4 + eu];
        float gg = g_lds[ 8 + eu][eb] + gx[ 8 + eu];
        float go = g_lds[12 + eu][eb] + gx[12 + eu];
        gi = __fdividef(1.0f, 1.0f + __expf(-gi));
        gf = __fdividef(1.0f, 1.0f + __expf(-gf));
        gg = 1.0f - __fdividef(2.0f, __expf(2.0f * gg) + 1.0f);
        go = __fdividef(1.0f, 1.0f + __expf(-go));
        c_reg = gf * c_reg + gi * gg;
        float hn = go * (1.0f - __fdividef(2.0f, __expf(2.0f * c_reg) + 1.0f));
        int hcol = cu * 4 + eu;
        cbuf[eb * 1024 + hcol] = c_reg;
        out[((size_t)t * 64 + eb) * 1024 + hcol] = hn;
        if (t == 511) {
            out[(size_t)512 * BH + eb * 1024 + hcol]      = hn;     // h_fin
            out[(size_t)512 * BH + BH + eb * 1024 + hcol] = c_reg;  // c_fin
        }
    }
}

// --------------------------------- host -------------------------------------
extern "C" void kernel_launch(void* const* d_in, const int* in_sizes, int n_in,
                              void* d_out, int out_size, void* d_ws, size_t ws_size,
                              hipStream_t stream)
{
    const float* x   = (const float*)d_in[0];
    const float* h0  = (const float*)d_in[1];
    const float* c0  = (const float*)d_in[2];
    const float* Wih = (const float*)d_in[3];
    const float* Whh = (const float*)d_in[4];
    const float* bih = (const float*)d_in[5];
    const float* bhh = (const float*)d_in[6];
    float* out = (float*)d_out;

    char*  ws   = (char*)d_ws;
    float* cbuf = (float*)ws;                       // 256KB c state

    // MFMA path layout: [cbuf 256KB][whi 8MB][wlo 8MB][xhi Tc*128KB][xlo ..][gxp Tc*1MB]
    const size_t FIXED = 262144 + 2 * 8388608;
    const long   PER   = 2 * 131072 + 1048576;      // per-Tc bytes
    long Tc = ((long)ws_size - (long)FIXED) / PER;
    bool use_mfma = (Tc >= 2);

    if (use_mfma) {
        if (Tc > 512) Tc = 512;
        Tc &= ~1L;
        ushort* whi = (ushort*)(ws + 262144);
        ushort* wlo = whi + 4194304;
        char*   var = ws + FIXED;
        ushort* xhi = (ushort*)var;
        ushort* xlo = (ushort*)(var + Tc * 131072);
        float*  gxp = (float*)(var + Tc * 262144);

        split_bf16<<<dim3(2048), dim3(256), 0, stream>>>(Wih, whi, wlo, 4194304L);
        for (int t0 = 0; t0 < 512; t0 += (int)Tc) {
            int chunk = (512 - t0 < (int)Tc) ? (512 - t0) : (int)Tc;
            split_bf16<<<dim3(4096), dim3(256), 0, stream>>>(
                x + (size_t)t0 * 65536, xhi, xlo, (long)chunk * 65536);
            gx_mfma<<<dim3(32, chunk * 64 / 128), dim3(256), 0, stream>>>(
                xhi, xlo, whi, wlo, bih, bhh, gxp);
            for (int trel = 0; trel < chunk; ++trel) {
                int t = t0 + trel;
                const float* hp = (t == 0) ? h0 : out + (size_t)(t - 1) * BH;
                const float* cp = (t == 0) ? c0 : cbuf;
                lstm_step<<<dim3(256), dim3(256), 0, stream>>>(
                    Whh, gxp, hp, cp, cbuf, out, t, trel);
            }
        }
    } else {
        // fp32 fallback (small ws): [cbuf][gxp Tc*1MB]
        float* gxp = (float*)(ws + 262144);
        long Tc2 = ((long)ws_size - 262144L) / 1048576L;
        if (Tc2 > 512) Tc2 = 512;
        Tc2 &= ~1L;
        if (Tc2 < 2) Tc2 = 2;
        for (int t0 = 0; t0 < 512; t0 += (int)Tc2) {
            int chunk = (512 - t0 < (int)Tc2) ? (512 - t0) : (int)Tc2;
            gx_gemm<<<dim3(32, chunk * 64 / BM), dim3(256), 0, stream>>>(
                x, Wih, bih, bhh, gxp, t0);
            for (int trel = 0; trel < chunk; ++trel) {
                int t = t0 + trel;
                const float* hp = (t == 0) ? h0 : out + (size_t)(t - 1) * BH;
                const float* cp = (t == 0) ? c0 : cbuf;
                lstm_step<<<dim3(256), dim3(256), 0, stream>>>(
                    Whh, gxp, hp, cp, cbuf, out, t, trel);
            }
        }
    }
}

// Round 7
// 9392.271 us; speedup vs baseline: 2.3574x; 2.2242x over previous
//
#include <hip/hip_runtime.h>
#include <hip/hip_bf16.h>

// LSTM layer: T=512, B=64, I=1024, H=1024, fp32.
// R6: recurrence step -> MFMA (bf16x3 split-K-across-waves), killing the
// VALU inner product that dominated (~37us/step at 1 wave/SIMD, no latency
// hiding). W_hh pre-split to bf16 hi/lo planes (A-frags straight from L2);
// h carried as double-buffered bf16 hi/lo planes written by the previous
// step's tail. LDS 132KB -> 20KB, 11 barriers -> 1.
// gx pipeline (split_bf16 + gx_mfma) unchanged from R5 (bench-validated).

#define BH 65536  // B*H floats

typedef __attribute__((ext_vector_type(8))) short bf16x8;  // 8 bf16 (4 VGPRs)
typedef __attribute__((ext_vector_type(4))) float f32x4;

__device__ inline ushort f2bf(float x) {
    __hip_bfloat16 b = __float2bfloat16(x);
    return *(ushort*)&b;
}
__device__ inline float bf2f(ushort u) {
    __hip_bfloat16 b = *(__hip_bfloat16*)&u;
    return __bfloat162float(b);
}

// ---------------- fp32 -> (hi,lo) bf16 planes (grid-stride) -----------------
__global__ void split_bf16(const float* __restrict__ src,
                           ushort* __restrict__ hi, ushort* __restrict__ lo,
                           long n)
{
    long i0 = ((long)blockIdx.x * blockDim.x + threadIdx.x) * 4;
    long stride = (long)gridDim.x * blockDim.x * 4;
    for (long e = i0; e < n; e += stride) {
        float4 v = *(const float4*)(src + e);
        ushort4 hv, lv;
        hv.x = f2bf(v.x); lv.x = f2bf(v.x - bf2f(hv.x));
        hv.y = f2bf(v.y); lv.y = f2bf(v.y - bf2f(hv.y));
        hv.z = f2bf(v.z); lv.z = f2bf(v.z - bf2f(hv.z));
        hv.w = f2bf(v.w); lv.w = f2bf(v.w - bf2f(hv.w));
        *(ushort4*)(hi + e) = hv;
        *(ushort4*)(lo + e) = lv;
    }
}

// ---------------- bf16x3 MFMA gx GEMM: gx = x·Wih^T + bias, permuted --------
__global__ __launch_bounds__(256)
void gx_mfma(const ushort* __restrict__ xhi, const ushort* __restrict__ xlo,
             const ushort* __restrict__ whi, const ushort* __restrict__ wlo,
             const float* __restrict__ bih, const float* __restrict__ bhh,
             float* __restrict__ gxp)
{
    __shared__ short lds[4][4096];      // planes Ahi,Alo,Bhi,Blo: [128][32] bf16
    const int tid  = threadIdx.x;
    const int lane = tid & 63;
    const int w    = tid >> 6;          // wave 0..3
    const int wm   = w >> 1, wn = w & 1;
    const int mt0  = blockIdx.y * 128;  // chunk-local m = trel*64 + b
    const int nt0  = blockIdx.x * 128;  // gate row r

    const int lr_ = w * 16 + (lane >> 2);
    const int lc_ = (lane & 3) * 8;

    f32x4 acc[4][4] = {};

    for (int kt = 0; kt < 1024; kt += 32) {
        uint4 rah[2], ral[2], rbh[2], rbl[2];
        #pragma unroll
        for (int s = 0; s < 2; ++s) {
            size_t ao = (size_t)(mt0 + s * 64 + lr_) * 1024 + kt + lc_;
            size_t bo = (size_t)(nt0 + s * 64 + lr_) * 1024 + kt + lc_;
            rah[s] = *(const uint4*)(xhi + ao);
            ral[s] = *(const uint4*)(xlo + ao);
            rbh[s] = *(const uint4*)(whi + bo);
            rbl[s] = *(const uint4*)(wlo + bo);
        }
        __syncthreads();
        #pragma unroll
        for (int s = 0; s < 2; ++s) {
            int off = s * 2048 + w * 512 + lane * 8;   // shorts
            *(uint4*)&lds[0][off] = rah[s];
            *(uint4*)&lds[1][off] = ral[s];
            *(uint4*)&lds[2][off] = rbh[s];
            *(uint4*)&lds[3][off] = rbl[s];
        }
        __syncthreads();
        bf16x8 ah[4], al[4], bh[4], bl[4];
        #pragma unroll
        for (int f = 0; f < 4; ++f) {
            int ar = (wm * 64 + f * 16 + (lane & 15)) * 32 + (lane >> 4) * 8;
            int br = (wn * 64 + f * 16 + (lane & 15)) * 32 + (lane >> 4) * 8;
            ah[f] = *(bf16x8*)&lds[0][ar];
            al[f] = *(bf16x8*)&lds[1][ar];
            bh[f] = *(bf16x8*)&lds[2][br];
            bl[f] = *(bf16x8*)&lds[3][br];
        }
        #pragma unroll
        for (int i = 0; i < 4; ++i)
            #pragma unroll
            for (int j = 0; j < 4; ++j) {
                acc[i][j] = __builtin_amdgcn_mfma_f32_16x16x32_bf16(ah[i], bh[j], acc[i][j], 0, 0, 0);
                acc[i][j] = __builtin_amdgcn_mfma_f32_16x16x32_bf16(ah[i], bl[j], acc[i][j], 0, 0, 0);
                acc[i][j] = __builtin_amdgcn_mfma_f32_16x16x32_bf16(al[i], bh[j], acc[i][j], 0, 0, 0);
            }
    }
    #pragma unroll
    for (int j = 0; j < 4; ++j) {
        int r = nt0 + wn * 64 + j * 16 + (lane & 15);
        float bias = bih[r] + bhh[r];
        int g = r >> 10, u = r & 1023;
        #pragma unroll
        for (int i = 0; i < 4; ++i) {
            #pragma unroll
            for (int e = 0; e < 4; ++e) {
                int m = mt0 + wm * 64 + i * 16 + (lane >> 4) * 4 + e;
                int trel = m >> 6, b = m & 63;
                gxp[(((size_t)trel * 256 + (u >> 2)) * 64 + b) * 16 + g * 4 + (u & 3)]
                    = acc[i][j][e] + bias;
            }
        }
    }
}

// ----------------------- fp32 gx GEMM (small-ws fallback) -------------------
#define BM 128
#define BN 128
#define BKg 16

__global__ __launch_bounds__(256, 2)
void gx_gemm(const float* __restrict__ x, const float* __restrict__ Wih,
             const float* __restrict__ bih, const float* __restrict__ bhh,
             float* __restrict__ gxp, int t0)
{
    __shared__ float As[BKg][BM + 4];
    __shared__ float Bs[BKg][BN + 4];
    const int tid  = threadIdx.x;
    const int nblk = blockIdx.x;
    const int mblk = blockIdx.y;
    const int lrow = tid >> 2;
    const int lkq  = (tid & 3) * 4;
    const int ty   = tid >> 4;
    const int tx   = tid & 15;

    const float* xb = x   + ((size_t)t0 * 64 + (size_t)mblk * BM) * 1024;
    const float* wb = Wih + (size_t)nblk * BN * 1024;

    float acc[8][8] = {};
    for (int kt = 0; kt < 1024; kt += BKg) {
        const int k0 = kt + lkq;
        float4 a0 = *(const float4*)(xb + (size_t)lrow        * 1024 + k0);
        float4 a1 = *(const float4*)(xb + (size_t)(lrow + 64) * 1024 + k0);
        float4 b0 = *(const float4*)(wb + (size_t)lrow        * 1024 + k0);
        float4 b1 = *(const float4*)(wb + (size_t)(lrow + 64) * 1024 + k0);
        __syncthreads();
        As[lkq + 0][lrow] = a0.x; As[lkq + 1][lrow] = a0.y;
        As[lkq + 2][lrow] = a0.z; As[lkq + 3][lrow] = a0.w;
        As[lkq + 0][lrow + 64] = a1.x; As[lkq + 1][lrow + 64] = a1.y;
        As[lkq + 2][lrow + 64] = a1.z; As[lkq + 3][lrow + 64] = a1.w;
        Bs[lkq + 0][lrow] = b0.x; Bs[lkq + 1][lrow] = b0.y;
        Bs[lkq + 2][lrow] = b0.z; Bs[lkq + 3][lrow] = b0.w;
        Bs[lkq + 0][lrow + 64] = b1.x; Bs[lkq + 1][lrow + 64] = b1.y;
        Bs[lkq + 2][lrow + 64] = b1.z; Bs[lkq + 3][lrow + 64] = b1.w;
        __syncthreads();
        #pragma unroll
        for (int kk = 0; kk < BKg; ++kk) {
            float4 af0 = *(float4*)&As[kk][ty * 8];
            float4 af1 = *(float4*)&As[kk][ty * 8 + 4];
            float4 bf0 = *(float4*)&Bs[kk][tx * 8];
            float4 bf1 = *(float4*)&Bs[kk][tx * 8 + 4];
            float a[8] = {af0.x, af0.y, af0.z, af0.w, af1.x, af1.y, af1.z, af1.w};
            float b[8] = {bf0.x, bf0.y, bf0.z, bf0.w, bf1.x, bf1.y, bf1.z, bf1.w};
            #pragma unroll
            for (int i = 0; i < 8; ++i)
                #pragma unroll
                for (int j = 0; j < 8; ++j)
                    acc[i][j] += a[i] * b[j];
        }
    }
    float bias[8];
    #pragma unroll
    for (int j = 0; j < 8; ++j) {
        int r = nblk * BN + tx * 8 + j;
        bias[j] = bih[r] + bhh[r];
    }
    #pragma unroll
    for (int i = 0; i < 8; ++i) {
        int ml   = mblk * BM + ty * 8 + i;
        int trel = ml >> 6, b = ml & 63;
        #pragma unroll
        for (int jj = 0; jj < 2; ++jj) {
            int r = nblk * BN + tx * 8 + jj * 4;
            int g = r >> 10, u = r & 1023;
            float4 v = make_float4(acc[i][jj*4+0] + bias[jj*4+0],
                                   acc[i][jj*4+1] + bias[jj*4+1],
                                   acc[i][jj*4+2] + bias[jj*4+2],
                                   acc[i][jj*4+3] + bias[jj*4+3]);
            *(float4*)(gxp + ((((size_t)trel * 256 + (u >> 2)) * 64 + b) << 4) + g * 4) = v;
        }
    }
}

// ---------------- one LSTM step: MFMA, split-K across 4 waves ----------------
// Block cu owns units cu*4..cu*4+3 (16 gate-rows rl = g*4+ul). Wave w = K-quarter.
// A-frags from Whh bf16 planes (global, L2-hot); B-frags from h bf16 planes.
__global__ __launch_bounds__(256)
void lstm_step_mfma(const ushort* __restrict__ whh_hi, const ushort* __restrict__ whh_lo,
                    const float* __restrict__ gxp,
                    const ushort* __restrict__ hin_hi, const ushort* __restrict__ hin_lo,
                    const float* __restrict__ cprev, float* __restrict__ cbuf,
                    ushort* __restrict__ hout_hi, ushort* __restrict__ hout_lo,
                    float* __restrict__ out, int t, int trel)
{
    __shared__ float part[4][64][20];   // [wave][b][r + pad4] = 20KB, 2-way-free
    const int tid  = threadIdx.x;
    const int lane = tid & 63;
    const int w    = tid >> 6;          // wave = k-quarter
    const int cu   = blockIdx.x;

    const int rl    = lane & 15;        // A row = local gate-row
    const size_t wrow = (size_t)((rl >> 2) * 1024 + cu * 4 + (rl & 3)) * 1024;
    const int klane = (lane >> 4) * 8;  // k offset within 32-k step
    const int kbase = w * 256;
    const int bq    = lane & 15;        // B col = batch within 16-group

    f32x4 acc[4] = {};                  // one per batch 16-group

    #pragma unroll
    for (int ks = 0; ks < 8; ++ks) {
        int k0 = kbase + ks * 32 + klane;
        bf16x8 a_hi = *(const bf16x8*)(whh_hi + wrow + k0);
        bf16x8 a_lo = *(const bf16x8*)(whh_lo + wrow + k0);
        #pragma unroll
        for (int nt = 0; nt < 4; ++nt) {
            size_t ho = (size_t)(nt * 16 + bq) * 1024 + k0;
            bf16x8 b_hi = *(const bf16x8*)(hin_hi + ho);
            bf16x8 b_lo = *(const bf16x8*)(hin_lo + ho);
            acc[nt] = __builtin_amdgcn_mfma_f32_16x16x32_bf16(a_hi, b_hi, acc[nt], 0, 0, 0);
            acc[nt] = __builtin_amdgcn_mfma_f32_16x16x32_bf16(a_hi, b_lo, acc[nt], 0, 0, 0);
            acc[nt] = __builtin_amdgcn_mfma_f32_16x16x32_bf16(a_lo, b_hi, acc[nt], 0, 0, 0);
        }
    }
    // D: col=lane&15 -> b within group; row=(lane>>4)*4+e -> gate-row r
    const int r0 = (lane >> 4) * 4;
    #pragma unroll
    for (int nt = 0; nt < 4; ++nt)
        *(f32x4*)&part[w][nt * 16 + bq][r0] = acc[nt];
    __syncthreads();

    // elementwise: thread -> (eb = tid>>2, eu = tid&3)
    const int eb = tid >> 2, eu = tid & 3;
    const float* gx = gxp + (((size_t)trel * 256 + cu) * 64 + eb) * 16;
    float pre[4];
    #pragma unroll
    for (int g = 0; g < 4; ++g) {
        int r = g * 4 + eu;
        pre[g] = part[0][eb][r] + part[1][eb][r] + part[2][eb][r] + part[3][eb][r]
               + gx[g * 4 + eu];
    }
    float gi = __fdividef(1.0f, 1.0f + __expf(-pre[0]));
    float gf = __fdividef(1.0f, 1.0f + __expf(-pre[1]));
    float gg = 1.0f - __fdividef(2.0f, __expf(2.0f * pre[2]) + 1.0f);
    float go = __fdividef(1.0f, 1.0f + __expf(-pre[3]));
    float c_reg = cprev[eb * 1024 + cu * 4 + eu];
    c_reg = gf * c_reg + gi * gg;
    float hn = go * (1.0f - __fdividef(2.0f, __expf(2.0f * c_reg) + 1.0f));

    int hcol = cu * 4 + eu;
    cbuf[eb * 1024 + hcol] = c_reg;
    out[((size_t)t * 64 + eb) * 1024 + hcol] = hn;
    ushort hh = f2bf(hn);
    hout_hi[eb * 1024 + hcol] = hh;
    hout_lo[eb * 1024 + hcol] = f2bf(hn - bf2f(hh));
    if (t == 511) {
        out[(size_t)512 * BH + eb * 1024 + hcol]      = hn;     // h_fin
        out[(size_t)512 * BH + BH + eb * 1024 + hcol] = c_reg;  // c_fin
    }
}

// --------------------------------- host -------------------------------------
extern "C" void kernel_launch(void* const* d_in, const int* in_sizes, int n_in,
                              void* d_out, int out_size, void* d_ws, size_t ws_size,
                              hipStream_t stream)
{
    const float* x   = (const float*)d_in[0];
    const float* h0  = (const float*)d_in[1];
    const float* c0  = (const float*)d_in[2];
    const float* Wih = (const float*)d_in[3];
    const float* Whh = (const float*)d_in[4];
    const float* bih = (const float*)d_in[5];
    const float* bhh = (const float*)d_in[6];
    float* out = (float*)d_out;

    char* ws = (char*)d_ws;
    float* cbuf = (float*)ws;                            // 256 KB

    // full-MFMA layout:
    // [cbuf 256K][wih_hi 8M][wih_lo 8M][whh_hi 8M][whh_lo 8M][hpl 512K]
    // [xhi Tc*128K][xlo Tc*128K][gxp Tc*1M]
    const size_t FIXED = 262144 + 4 * 8388608L + 524288;
    const long   PER   = 2 * 131072L + 1048576L;
    long Tc = ((long)ws_size - (long)FIXED) / PER;

    if (Tc >= 2) {
        if (Tc > 512) Tc = 512;
        Tc &= ~1L;
        ushort* wih_hi = (ushort*)(ws + 262144);
        ushort* wih_lo = wih_hi + 4194304;
        ushort* whh_hi = wih_lo + 4194304;
        ushort* whh_lo = whh_hi + 4194304;
        ushort* hpl    = whh_lo + 4194304;   // [buf 2][plane 2][BH] ushorts
        char*   var    = ws + FIXED;
        ushort* xhi    = (ushort*)var;
        ushort* xlo    = (ushort*)(var + Tc * 131072);
        float*  gxp    = (float*)(var + Tc * 262144);

        split_bf16<<<dim3(2048), dim3(256), 0, stream>>>(Wih, wih_hi, wih_lo, 4194304L);
        split_bf16<<<dim3(2048), dim3(256), 0, stream>>>(Whh, whh_hi, whh_lo, 4194304L);
        split_bf16<<<dim3(64),   dim3(256), 0, stream>>>(h0, hpl + 2 * BH, hpl + 3 * BH, (long)BH);

        for (int t0 = 0; t0 < 512; t0 += (int)Tc) {
            int chunk = (512 - t0 < (int)Tc) ? (512 - t0) : (int)Tc;
            split_bf16<<<dim3(4096), dim3(256), 0, stream>>>(
                x + (size_t)t0 * BH, xhi, xlo, (long)chunk * BH);
            gx_mfma<<<dim3(32, chunk / 2), dim3(256), 0, stream>>>(
                xhi, xlo, wih_hi, wih_lo, bih, bhh, gxp);
            for (int trel = 0; trel < chunk; ++trel) {
                int t = t0 + trel;
                int rb = (t + 1) & 1, wb = t & 1;     // read/write plane buffers
                const float* cp = (t == 0) ? c0 : cbuf;
                lstm_step_mfma<<<dim3(256), dim3(256), 0, stream>>>(
                    whh_hi, whh_lo, gxp,
                    hpl + rb * 2 * BH, hpl + rb * 2 * BH + BH,
                    cp, cbuf,
                    hpl + wb * 2 * BH, hpl + wb * 2 * BH + BH,
                    out, t, trel);
            }
        }
    } else {
        // small-ws fallback: fp32 gx GEMM + MFMA step
        // [cbuf 256K][whh_hi 8M][whh_lo 8M][hpl 512K][gxp Tc*1M]
        ushort* whh_hi = (ushort*)(ws + 262144);
        ushort* whh_lo = whh_hi + 4194304;
        ushort* hpl    = whh_lo + 4194304;
        const size_t FIXED2 = 262144 + 2 * 8388608L + 524288;
        float* gxp = (float*)(ws + FIXED2);
        long Tc2 = ((long)ws_size - (long)FIXED2) / 1048576L;
        if (Tc2 > 512) Tc2 = 512;
        Tc2 &= ~1L;
        if (Tc2 < 2) Tc2 = 2;

        split_bf16<<<dim3(2048), dim3(256), 0, stream>>>(Whh, whh_hi, whh_lo, 4194304L);
        split_bf16<<<dim3(64),   dim3(256), 0, stream>>>(h0, hpl + 2 * BH, hpl + 3 * BH, (long)BH);

        for (int t0 = 0; t0 < 512; t0 += (int)Tc2) {
            int chunk = (512 - t0 < (int)Tc2) ? (512 - t0) : (int)Tc2;
            gx_gemm<<<dim3(32, chunk * 64 / BM), dim3(256), 0, stream>>>(
                x, Wih, bih, bhh, gxp, t0);
            for (int trel = 0; trel < chunk; ++trel) {
                int t = t0 + trel;
                int rb = (t + 1) & 1, wb = t & 1;
                const float* cp = (t == 0) ? c0 : cbuf;
                lstm_step_mfma<<<dim3(256), dim3(256), 0, stream>>>(
                    whh_hi, whh_lo, gxp,
                    hpl + rb * 2 * BH, hpl + rb * 2 * BH + BH,
                    cp, cbuf,
                    hpl + wb * 2 * BH, hpl + wb * 2 * BH + BH,
                    out, t, trel);
            }
        }
    }
}